// Round 19
// baseline (37.882 us; speedup 1.0000x reference)
//
#include <hip/hip_runtime.h>
#include <math.h>

typedef __attribute__((ext_vector_type(8))) _Float16 f16x8;
typedef __attribute__((ext_vector_type(2))) _Float16 f16x2;
typedef __attribute__((ext_vector_type(4))) float f32x4;

// ============================ MFMA fused kernel v17 ============================
// v17 = v16 (37.4 µs) + T3/T4 COUNTED-VMCNT PIPELINE. v14/v16's per-step
// __syncthreads drains vmcnt(0): the chunk DMA issued at step start is forced
// complete by step end -> ~300cy exposed latency per step, the invariant stall.
// Now: 4 W-buffers, stage chunk S+3 at step S (overwrites buf[(S-1)%4], all
// reads of which finished before the step S-1 barrier -> ONE raw s_barrier per
// step, no drain). Per-wave s_waitcnt vmcnt(N) (N = 2 x in-flight chunks)
// before the barrier makes chunk S+1 ready for all waves; DMA stays 3 deep in
// flight across barriers. x/bias pinned to registers first so vmcnt counts
// only DMA. H is wave-private (no lgkm barrier needed).

#define TPB 256
#define BM  128
#define HSTRIDE 272                    // 128 cols x 2B + 16B pad
#define W_OFF   34816                  // H bytes
#define LDS_TOT (34816 + 4 * 8192)     // 67584 B -> 2 blocks/CU

#if __has_builtin(__builtin_amdgcn_global_load_lds)
#define HAVE_GLL 1
typedef const __attribute__((address_space(1))) unsigned int glb_u32;
typedef __attribute__((address_space(3))) unsigned int lds_u32;
#else
#define HAVE_GLL 0
#endif

#if HAVE_GLL
#define WAIT_DMA(N) asm volatile("s_waitcnt vmcnt(" #N ")" ::: "memory")
#else
#define WAIT_DMA(N) asm volatile("s_waitcnt vmcnt(0) lgkmcnt(0)" ::: "memory")
#endif
#define BAR() __builtin_amdgcn_s_barrier()
#define PIN(f) asm volatile("" : "+v"(f))

__global__ __launch_bounds__(TPB, 2) void kan_mfma_kernel(
    const float* __restrict__ x, const _Float16* __restrict__ W0t,
    const _Float16* __restrict__ W1t, const float* __restrict__ bias0,
    const float* __restrict__ bias1, float* __restrict__ out)
{
    __shared__ char smem[LDS_TOT];
    const int tid  = threadIdx.x;
    const int lane = tid & 63;
    const int wid  = tid >> 6;          // 4 waves, disjoint 32-row strips
    const int gq   = lane >> 4;         // k-group 0..3
    const int lm   = lane & 15;
    const int wavebase = wid * 32;
    const long rowbase = (long)blockIdx.x * BM;

    // stage 8KB chunk into buf: per wave 2 x (64 lanes x 16B); LDS dest linear.
    auto stageChunk = [&](const char* gsrc_chunk, int bufoff) {
#if HAVE_GLL
        const char* gs = gsrc_chunk + wid * 2048 + lane * 16;
        char* ls = smem + W_OFF + bufoff + wid * 2048;
        __builtin_amdgcn_global_load_lds((glb_u32*)gs, (lds_u32*)ls, 16, 0, 0);
        __builtin_amdgcn_global_load_lds((glb_u32*)(gs + 1024), (lds_u32*)(ls + 1024), 16, 0, 0);
#else
        float4 a = *(const float4*)(gsrc_chunk + tid * 32);
        float4 b = *(const float4*)(gsrc_chunk + tid * 32 + 16);
        *(float4*)(smem + W_OFF + bufoff + tid * 32)      = a;
        *(float4*)(smem + W_OFF + bufoff + tid * 32 + 16) = b;
#endif
    };

#if __has_builtin(__builtin_amdgcn_cvt_pkrtz)
    auto pk2 = [](float a, float b) -> f16x2 {
        return (f16x2)__builtin_amdgcn_cvt_pkrtz(a, b);
    };
#else
    auto pk2 = [](float a, float b) -> f16x2 {
        return f16x2{(_Float16)a, (_Float16)b};
    };
#endif
#if __has_builtin(__builtin_amdgcn_rcpf)
    auto frcp = [](float a) -> float { return __builtin_amdgcn_rcpf(a); };
#else
    auto frcp = [](float a) -> float { return 1.0f / a; };
#endif

    // features for 8 values -> 4 fragments {base, gi, s1, s1*gi}
    auto buildFeats4 = [&](const float* v, f16x8* dst) {
        union U { f16x8 v8; f16x2 h2[4]; } u0, u1, u2, u3;
        #pragma unroll
        for (int q = 0; q < 4; ++q) {
            float va = v[2 * q], vb = v[2 * q + 1];
            float ba = va * frcp(1.0f + __expf(-va));
            float bb = vb * frcp(1.0f + __expf(-vb));
            float ga = fminf(fmaxf(va, -1.f), 1.f) + 1.f;   // [0,2]
            float gb = fminf(fmaxf(vb, -1.f), 1.f) + 1.f;
            float s1a = (ga >= 1.f) ? 1.f : 0.f;
            float s1b = (gb >= 1.f) ? 1.f : 0.f;
            float sga = (ga >= 1.f) ? ga : 0.f;
            float sgb = (gb >= 1.f) ? gb : 0.f;
            u0.h2[q] = pk2(ba, bb);
            u1.h2[q] = pk2(ga, gb);
            u2.h2[q] = pk2(s1a, s1b);
            u3.h2[q] = pk2(sga, sgb);
        }
        dst[0] = u0.v8; dst[1] = u1.v8; dst[2] = u2.v8; dst[3] = u3.v8;
    };

    // ---------------- bias fragments (per-column, fp32) ----------------
    float b0v[8], b1v[4];
    #pragma unroll
    for (int nf = 0; nf < 8; ++nf) b0v[nf] = bias0[nf * 16 + lm];
    #pragma unroll
    for (int nf = 0; nf < 4; ++nf) b1v[nf] = bias1[nf * 16 + lm];

    // ---------------- load x values for both i-halves ----------------
    float v0[2][8], v1[2][8];           // [mi][e]: ih=0 (i=gq*8..), ih=1 (i=32+gq*8..)
    #pragma unroll
    for (int mi = 0; mi < 2; ++mi) {
        const float* xp = x + (rowbase + wavebase + mi * 16 + lm) * 64 + gq * 8;
        float4 a0 = *(const float4*)(xp);
        float4 a1 = *(const float4*)(xp + 4);
        float4 a2 = *(const float4*)(xp + 32);
        float4 a3 = *(const float4*)(xp + 36);
        v0[mi][0]=a0.x; v0[mi][1]=a0.y; v0[mi][2]=a0.z; v0[mi][3]=a0.w;
        v0[mi][4]=a1.x; v0[mi][5]=a1.y; v0[mi][6]=a1.z; v0[mi][7]=a1.w;
        v1[mi][0]=a2.x; v1[mi][1]=a2.y; v1[mi][2]=a2.z; v1[mi][3]=a2.w;
        v1[mi][4]=a3.x; v1[mi][5]=a3.y; v1[mi][6]=a3.z; v1[mi][7]=a3.w;
    }
    // pin all pre-loop loads into registers so vmcnt tracks ONLY our W DMA
    #pragma unroll
    for (int mi = 0; mi < 2; ++mi)
        #pragma unroll
        for (int e = 0; e < 8; ++e) { PIN(v0[mi][e]); PIN(v1[mi][e]); }
    #pragma unroll
    for (int nf = 0; nf < 8; ++nf) PIN(b0v[nf]);
    #pragma unroll
    for (int nf = 0; nf < 4; ++nf) PIN(b1v[nf]);

    // ---------------- layer 0: 8 chunks, 4-buffer 3-deep pipeline ----------------
    f32x4 acc[2][8] = {};
    f16x8 fr[2][4];
    {
        const char* w0 = (const char*)W0t;
        const int lb0 = (gq * 128 + lm) * 16;    // + nf*256 within chunk

        stageChunk(w0 + 0 * 8192, 0 * 8192);
        stageChunk(w0 + 1 * 8192, 1 * 8192);
        stageChunk(w0 + 2 * 8192, 2 * 8192);
        buildFeats4(v0[0], fr[0]);
        buildFeats4(v0[1], fr[1]);
        WAIT_DMA(4);                     // own chunk0 loads done
        BAR();                           // all waves' chunk0 done

#define L0_STEP(S, C, VN) do {                                                \
        const char* wb = smem + W_OFF + ((S) % 4) * 8192;                     \
        f16x8 bt[8];                                                          \
        _Pragma("unroll")                                                     \
        for (int nf = 0; nf < 8; ++nf)                                        \
            bt[nf] = *(const f16x8*)(wb + lb0 + nf * 256);                    \
        _Pragma("unroll")                                                     \
        for (int mi = 0; mi < 2; ++mi) {                                      \
            f16x8 a = fr[mi][C];                                              \
            _Pragma("unroll")                                                 \
            for (int nf = 0; nf < 8; ++nf)                                    \
                acc[mi][nf] = __builtin_amdgcn_mfma_f32_16x16x32_f16(         \
                    a, bt[nf], acc[mi][nf], 0, 0, 0);                         \
        }                                                                     \
        if ((S) < 5)                                                          \
            stageChunk(w0 + ((S) + 3) * 8192, (((S) + 3) % 4) * 8192);        \
        if ((S) < 7) { WAIT_DMA(VN); BAR(); }                                 \
    } while (0)

        L0_STEP(0, 0, 4); L0_STEP(1, 1, 4);
        L0_STEP(2, 2, 4); L0_STEP(3, 3, 4);
        buildFeats4(v1[0], fr[0]);
        buildFeats4(v1[1], fr[1]);
        L0_STEP(4, 0, 4); L0_STEP(5, 1, 2);
        L0_STEP(6, 2, 0); L0_STEP(7, 3, 0);
#undef L0_STEP
    }

    // ---------------- transition: H (+bias0, wave-private) ; stage L1 chunks 0..2 ----------------
    {
        const char* w1 = (const char*)W1t;
        #pragma unroll
        for (int mi = 0; mi < 2; ++mi)
            #pragma unroll
            for (int nf = 0; nf < 8; ++nf)
                #pragma unroll
                for (int rg = 0; rg < 4; ++rg)
                    *(_Float16*)(smem + (wavebase + mi * 16 + gq * 4 + rg) * HSTRIDE
                                 + (nf * 16 + lm) * 2) = (_Float16)(acc[mi][nf][rg] + b0v[nf]);
        // bufs 0,1,2: last L0 reads were steps 4,5,6 -- all waves passed the
        // step-6 barrier (step 7 reads buf3 only) -> safe to overwrite.
        stageChunk(w1 + 0 * 8192, 0 * 8192);
        stageChunk(w1 + 1 * 8192, 1 * 8192);
        stageChunk(w1 + 2 * 8192, 2 * 8192);
        WAIT_DMA(4);                     // own L1-chunk0 loads done (L0 DMA drained at S=6)
        BAR();                           // all waves' L1-chunk0 done
    }

    // ---------------- layer 1: 8 super-chunks (8KB = 2 sub-steps), same pipeline ----------------
    f32x4 accO[2][4] = {};
    {
        const char* w1 = (const char*)W1t;
        const int lb1 = (gq * 64 + lm) * 16;     // + nf*256 within 4KB half

#define L1_SUB(BUFOFF, C) do {                                                \
        const char* wb = smem + W_OFF + (BUFOFF);                             \
        f16x8 bt[4];                                                          \
        _Pragma("unroll")                                                     \
        for (int nf = 0; nf < 4; ++nf)                                        \
            bt[nf] = *(const f16x8*)(wb + lb1 + nf * 256);                    \
        _Pragma("unroll")                                                     \
        for (int mi = 0; mi < 2; ++mi) {                                      \
            f16x8 a = fr[mi][C];                                              \
            _Pragma("unroll")                                                 \
            for (int nf = 0; nf < 4; ++nf)                                    \
                accO[mi][nf] = __builtin_amdgcn_mfma_f32_16x16x32_f16(        \
                    a, bt[nf], accO[mi][nf], 0, 0, 0);                        \
        }                                                                     \
    } while (0)

#define L1_STEP(SG, C0, C1, VN) do {                                          \
        L1_SUB(((SG) % 4) * 8192, C0);                                        \
        L1_SUB(((SG) % 4) * 8192 + 4096, C1);                                 \
        if ((SG) < 5)                                                         \
            stageChunk(w1 + ((SG) + 3) * 8192, (((SG) + 3) % 4) * 8192);      \
        if ((SG) < 7) { WAIT_DMA(VN); BAR(); }                                \
    } while (0)

#define L1_FEATS(HALF, IH) do {                                               \
        _Pragma("unroll")                                                     \
        for (int mi = 0; mi < 2; ++mi) {                                      \
            const char* hrow = smem + (wavebase + mi * 16 + lm) * HSTRIDE;    \
            f16x8 hv = *(const f16x8*)(hrow + ((HALF) * 64 + (IH) * 32 + gq * 8) * 2); \
            float v[8];                                                       \
            _Pragma("unroll")                                                 \
            for (int e = 0; e < 8; ++e) v[e] = (float)hv[e];                  \
            buildFeats4(v, fr[mi]);                                           \
        }                                                                     \
    } while (0)

        L1_FEATS(0, 0);
        L1_STEP(0, 0, 1, 4); L1_STEP(1, 2, 3, 4);
        L1_FEATS(0, 1);
        L1_STEP(2, 0, 1, 4); L1_STEP(3, 2, 3, 4);
        L1_FEATS(1, 0);
        L1_STEP(4, 0, 1, 4); L1_STEP(5, 2, 3, 2);
        L1_FEATS(1, 1);
        L1_STEP(6, 0, 1, 0); L1_STEP(7, 2, 3, 0);
#undef L1_SUB
#undef L1_STEP
#undef L1_FEATS
    }

    // ---------------- store out (+bias1) ----------------
    float* og = out + (rowbase + wavebase) * 64;
    #pragma unroll
    for (int mi = 0; mi < 2; ++mi)
        #pragma unroll
        for (int nf = 0; nf < 4; ++nf)
            #pragma unroll
            for (int rg = 0; rg < 4; ++rg)
                og[(mi * 16 + gq * 4 + rg) * 64 + nf * 16 + lm] = accO[mi][nf][rg] + b1v[nf];
}

// ------------- pre-kernel: fold weights + wide-parallel bias (= v13/v14/v16) -------------
// blocks 0..255: weight fold.  blocks 256..271: bias0 (16 blk x 8 cols, 2-iter).
// blocks 272..287: bias1 (16 blk x 4 cols, 2-iter).
// Feature order q: {base, gi, s1, s1*gi}.  Per edge:
//   P0 = cp.bv0 ; Q0 = cp.(bv1-bv0) ; P1 = cp.(2bv1-bv2) ; Q1 = cp.(bv2-bv1)
//   w = imp * {bw, sw*Q0, sw*(P1-P0), sw*(Q1-Q0)};  bias_j = sum_i imp*sw*P0
// W0t flat f = ((s*4+g)*128+n)*8+e ; s=ih*4+q ; i=ih*32+g*8+e ; edge=i*128+n
// W1t flat f = (((half*8+s)*4+g)*64+n)*8+e ; i2=half*64+ih*32+g*8+e
__global__ __launch_bounds__(256) void kan_combine_w(
    const float* __restrict__ cp0, const float* __restrict__ bw0,
    const float* __restrict__ sw0, const float* __restrict__ imp0,
    const float* __restrict__ cp1, const float* __restrict__ bw1,
    const float* __restrict__ sw1, const float* __restrict__ imp1,
    _Float16* __restrict__ W0t, _Float16* __restrict__ W1t,
    float* __restrict__ bias0, float* __restrict__ bias1)
{
    float bvv[3][5];
    #pragma unroll
    for (int g = 0; g < 3; ++g) {
        float gv = (float)g - 1.0f;
        float e[5]; float s = 0.f;
        #pragma unroll
        for (int i = 0; i < 5; ++i) {
            float cc = -0.8125f + 0.325f * (float)i;
            float d  = (gv - cc) * (1.0f / 0.65f);
            e[i] = __expf(-d * d); s += e[i];
        }
        float inv = 1.0f / (s + 1e-6f);
        #pragma unroll
        for (int i = 0; i < 5; ++i) bvv[g][i] = e[i] * inv;
    }

    auto wval = [&](const float* cp, float bw, float sw, float imp, int q) -> float {
        if (q == 0) return imp * bw;
        float P0 = 0.f, Q0 = 0.f, P1 = 0.f, Q1 = 0.f;
        #pragma unroll
        for (int c = 0; c < 5; ++c) {
            P0 += cp[c] * bvv[0][c];
            Q0 += cp[c] * (bvv[1][c] - bvv[0][c]);
            P1 += cp[c] * (2.f * bvv[1][c] - bvv[2][c]);
            Q1 += cp[c] * (bvv[2][c] - bvv[1][c]);
        }
        float r = (q == 1) ? Q0 : (q == 2) ? (P1 - P0) : (Q1 - Q0);
        return imp * sw * r;
    };
    auto p0val = [&](const float* cp) -> float {
        float P0 = 0.f;
        #pragma unroll
        for (int c = 0; c < 5; ++c) P0 += cp[c] * bvv[0][c];
        return P0;
    };

    const int bx = blockIdx.x;
    const int t  = threadIdx.x;

    if (bx < 256) {
        int f = bx * 256 + t;
        if (f < 32768) {
            int e = f & 7, n = (f >> 3) & 127, g = (f >> 10) & 3, s = f >> 12;
            int ih = s >> 2, q = s & 3;
            int i = ih * 32 + g * 8 + e;
            int edge = i * 128 + n;
            W0t[f] = (_Float16)wval(cp0 + edge * 5, bw0[edge], sw0[edge], imp0[edge], q);
        } else {
            int f2 = f - 32768;
            int e = f2 & 7, n = (f2 >> 3) & 63, g = (f2 >> 9) & 3;
            int tq = f2 >> 11;
            int half = tq >> 3, s = tq & 7;
            int ih = s >> 2, q = s & 3;
            int i2 = half * 64 + ih * 32 + g * 8 + e;
            int edge = i2 * 64 + n;
            W1t[f2] = (_Float16)wval(cp1 + edge * 5, bw1[edge], sw1[edge], imp1[edge], q);
        }
    } else if (bx < 272) {
        __shared__ float part[256];
        int bb = bx - 256;
        int jj = t >> 5, split = t & 31;
        int j = bb * 8 + jj;
        float s = 0.f;
        #pragma unroll
        for (int k = 0; k < 2; ++k) {
            int i = split * 2 + k;
            int edge = i * 128 + j;
            s += imp0[edge] * sw0[edge] * p0val(cp0 + edge * 5);
        }
        part[t] = s;
        __syncthreads();
        if (t < 8) {
            float acc = 0.f;
            #pragma unroll
            for (int k = 0; k < 32; ++k) acc += part[t * 32 + k];
            bias0[bb * 8 + t] = acc;
        }
    } else {
        __shared__ float part[256];
        int bb = bx - 272;
        int jj = t >> 6, split = t & 63;
        int j = bb * 4 + jj;
        float s = 0.f;
        #pragma unroll
        for (int k = 0; k < 2; ++k) {
            int i2 = split * 2 + k;
            int edge = i2 * 64 + j;
            s += imp1[edge] * sw1[edge] * p0val(cp1 + edge * 5);
        }
        part[t] = s;
        __syncthreads();
        if (t < 4) {
            float acc = 0.f;
            #pragma unroll
            for (int k = 0; k < 64; ++k) acc += part[t * 64 + k];
            bias1[bb * 4 + t] = acc;
        }
    }
}

// ===================== fallback: proven fp32 kernel (round 2) =====================
#define NTHR 256
#define JT 32
#define WS8 8

#define STAGE_L0(JBASE) do {                                                  \
    _Pragma("unroll")                                                         \
    for (int p = 0; p < 8; ++p) {                                             \
        int idx = tid + p * NTHR;                                             \
        int i  = idx >> 5;                                                    \
        int jj = idx & 31;                                                    \
        int e  = i * 128 + (JBASE) + jj;                                      \
        float im = imp0[e];                                                   \
        float wb = bw0[e] * im;                                               \
        float ws = sw0[e] * im;                                               \
        const float* cp = cp0 + e * 5;                                        \
        float* wp = wbuf + idx * WS8;                                         \
        wp[0] = wb;                                                           \
        wp[1] = ws * cp[0]; wp[2] = ws * cp[1]; wp[3] = ws * cp[2];           \
        wp[4] = ws * cp[3]; wp[5] = ws * cp[4];                               \
    }                                                                         \
} while (0)

#define STAGE_L1(IBASE, JBASE) do {                                           \
    _Pragma("unroll")                                                         \
    for (int p = 0; p < 8; ++p) {                                             \
        int idx = tid + p * NTHR;                                             \
        int ii = idx >> 5;                                                    \
        int jj = idx & 31;                                                    \
        int e  = ((IBASE) + ii) * 64 + (JBASE) + jj;                          \
        float im = imp1[e];                                                   \
        float wb = bw1[e] * im;                                               \
        float ws = sw1[e] * im;                                               \
        const float* cp = cp1 + e * 5;                                        \
        float* wp = wbuf + idx * WS8;                                         \
        wp[0] = wb;                                                           \
        wp[1] = ws * cp[0]; wp[2] = ws * cp[1]; wp[3] = ws * cp[2];           \
        wp[4] = ws * cp[3]; wp[5] = ws * cp[4];                               \
    }                                                                         \
} while (0)

#define COMPUTE_TILE(ACC) do {                                                \
    _Pragma("unroll 2")                                                       \
    for (int i = 0; i < 64; ++i) {                                            \
        float v  = vbuf[i][tid];                                              \
        float sg = 1.0f / (1.0f + __expf(-v));                                \
        float base = v * sg;                                                  \
        float xc = fminf(fmaxf(v, -1.0f), 1.0f);                              \
        float gi = xc + 1.0f;                                                 \
        int lo = (int)gi; lo = (lo > 2) ? 2 : lo;                             \
        float fr = gi - (float)lo;                                            \
        int hi = (fr > 0.0f) ? (lo + 1) : lo;                                 \
        float b0 = bvt[lo][0]; b0 += (bvt[hi][0] - b0) * fr;                  \
        float b1 = bvt[lo][1]; b1 += (bvt[hi][1] - b1) * fr;                  \
        float b2 = bvt[lo][2]; b2 += (bvt[hi][2] - b2) * fr;                  \
        float b3 = bvt[lo][3]; b3 += (bvt[hi][3] - b3) * fr;                  \
        float b4 = bvt[lo][4]; b4 += (bvt[hi][4] - b4) * fr;                  \
        const float* wr = wbuf + i * (JT * WS8);                              \
        _Pragma("unroll")                                                     \
        for (int jj = 0; jj < JT; ++jj) {                                     \
            const float* wp = wr + jj * WS8;                                  \
            float a = ACC[jj];                                                \
            a = fmaf(wp[0], base, a);                                         \
            a = fmaf(wp[1], b0, a);                                           \
            a = fmaf(wp[2], b1, a);                                           \
            a = fmaf(wp[3], b2, a);                                           \
            a = fmaf(wp[4], b3, a);                                           \
            a = fmaf(wp[5], b4, a);                                           \
            ACC[jj] = a;                                                      \
        }                                                                     \
    }                                                                         \
} while (0)

__global__ __launch_bounds__(NTHR) void kan_fused_kernel(
    const float* __restrict__ x,
    const float* __restrict__ cp0, const float* __restrict__ bw0,
    const float* __restrict__ sw0, const float* __restrict__ imp0,
    const float* __restrict__ cp1, const float* __restrict__ bw1,
    const float* __restrict__ sw1, const float* __restrict__ imp1,
    float* __restrict__ out)
{
    __shared__ float vbuf[64][NTHR + 1];
    __shared__ float wbuf[64 * JT * WS8];
    __shared__ float bvt[3][8];

    const int tid = threadIdx.x;

    if (tid < 3) {
        float gv = -1.0f + (float)tid;
        float e[5];
        float s = 0.0f;
        #pragma unroll
        for (int i = 0; i < 5; ++i) {
            float c = -0.8125f + 0.325f * (float)i;
            float d = (gv - c) * (1.0f / 0.65f);
            e[i] = expf(-d * d);
            s += e[i];
        }
        float inv = 1.0f / (s + 1e-6f);
        #pragma unroll
        for (int i = 0; i < 5; ++i) bvt[tid][i] = e[i] * inv;
    }

    {
        const float4* xg = (const float4*)(x + (size_t)blockIdx.x * (NTHR * 64));
        #pragma unroll
        for (int it = 0; it < 16; ++it) {
            int e4 = tid + it * NTHR;
            float4 v = xg[e4];
            int r  = e4 >> 4;
            int ib = (e4 & 15) << 2;
            vbuf[ib + 0][r] = v.x;
            vbuf[ib + 1][r] = v.y;
            vbuf[ib + 2][r] = v.z;
            vbuf[ib + 3][r] = v.w;
        }
    }
    __syncthreads();

    float h0[32] = {}, h1[32] = {}, h2[32] = {}, h3[32] = {};
    STAGE_L0(0);   __syncthreads(); COMPUTE_TILE(h0); __syncthreads();
    STAGE_L0(32);  __syncthreads(); COMPUTE_TILE(h1); __syncthreads();
    STAGE_L0(64);  __syncthreads(); COMPUTE_TILE(h2); __syncthreads();
    STAGE_L0(96);  __syncthreads(); COMPUTE_TILE(h3); __syncthreads();

    #pragma unroll
    for (int i = 0; i < 32; ++i) vbuf[i][tid] = h0[i];
    #pragma unroll
    for (int i = 0; i < 32; ++i) vbuf[32 + i][tid] = h1[i];

    float o0[32] = {}, o1[32] = {};
    STAGE_L1(0, 0);   __syncthreads(); COMPUTE_TILE(o0); __syncthreads();
    STAGE_L1(0, 32);  __syncthreads(); COMPUTE_TILE(o1); __syncthreads();

    #pragma unroll
    for (int i = 0; i < 32; ++i) vbuf[i][tid] = h2[i];
    #pragma unroll
    for (int i = 0; i < 32; ++i) vbuf[32 + i][tid] = h3[i];

    STAGE_L1(64, 0);  __syncthreads(); COMPUTE_TILE(o0); __syncthreads();
    STAGE_L1(64, 32); __syncthreads(); COMPUTE_TILE(o1);

    float4* og = (float4*)(out + (size_t)blockIdx.x * (NTHR * 64) + (size_t)tid * 64);
    #pragma unroll
    for (int q = 0; q < 8; ++q)
        og[q] = make_float4(o0[4 * q + 0], o0[4 * q + 1], o0[4 * q + 2], o0[4 * q + 3]);
    #pragma unroll
    for (int q = 0; q < 8; ++q)
        og[8 + q] = make_float4(o1[4 * q + 0], o1[4 * q + 1], o1[4 * q + 2], o1[4 * q + 3]);
}

// =================================== launch ===================================
extern "C" void kernel_launch(void* const* d_in, const int* in_sizes, int n_in,
                              void* d_out, int out_size, void* d_ws, size_t ws_size,
                              hipStream_t stream) {
    const float* x    = (const float*)d_in[0];
    const float* cp0  = (const float*)d_in[1];
    const float* bw0  = (const float*)d_in[2];
    const float* sw0  = (const float*)d_in[3];
    const float* imp0 = (const float*)d_in[4];
    const float* cp1  = (const float*)d_in[5];
    const float* bw1  = (const float*)d_in[6];
    const float* sw1  = (const float*)d_in[7];
    const float* imp1 = (const float*)d_in[8];
    float* out = (float*)d_out;

    const int B = in_sizes[0] / 64;                 // 131072
    const size_t need = 65536 * sizeof(_Float16) + 192 * sizeof(float);

    if (ws_size >= need && (B % BM) == 0) {
        _Float16* W0t = (_Float16*)d_ws;
        _Float16* W1t = W0t + 32768;
        float* bias0 = (float*)(W1t + 32768);
        float* bias1 = bias0 + 128;
        kan_combine_w<<<288, 256, 0, stream>>>(cp0, bw0, sw0, imp0,
                                               cp1, bw1, sw1, imp1,
                                               W0t, W1t, bias0, bias1);
        kan_mfma_kernel<<<B / BM, TPB, 0, stream>>>(x, W0t, W1t, bias0, bias1, out);
    } else {
        kan_fused_kernel<<<B / NTHR, NTHR, 0, stream>>>(
            x, cp0, bw0, sw0, imp0, cp1, bw1, sw1, imp1, out);
    }
}

// Round 20
// 37.416 us; speedup vs baseline: 1.0124x; 1.0124x over previous
//
#include <hip/hip_runtime.h>
#include <math.h>

typedef __attribute__((ext_vector_type(8))) _Float16 f16x8;
typedef __attribute__((ext_vector_type(2))) _Float16 f16x2;
typedef __attribute__((ext_vector_type(4))) float f32x4;

// ============================ MFMA fused kernel v18 = v16 ============================
// FINAL CONSOLIDATION. v16 measured 37.40 µs (best; v14 reg-staged 37.40,
// v13 37.58, v17 counted-vmcnt 37.88 -- all staging/sync variants within
// noise). Plateau diagnosis: 8 waves/CU give implicit cross-block overlap
// that already hides the per-step drain; remaining time = three ~30%-busy
// pipes (MFMA/VALU/LDS ~10us each + 8us HBM) serialized by the per-step
// {feature-VALU -> ds_read -> MFMA} dependence chain.
// Structure: BM=128, 4 waves x 32 rows; K=256 {silu,gi,s1,s1*gi} features
// (algebraic collapse of the G=3 spline + per-column bias fold); W staged
// 8KB/step via global_load_lds DMA, double-buffered; H wave-private in LDS.

#define TPB 256
#define BM  128
#define HSTRIDE 272                    // 128 cols x 2B + 16B pad
#define W_OFF   34816                  // H bytes
#define LDS_TOT (34816 + 16384)        // 51200 B -> 3 blocks/CU

#if __has_builtin(__builtin_amdgcn_global_load_lds)
#define HAVE_GLL 1
typedef const __attribute__((address_space(1))) unsigned int glb_u32;
typedef __attribute__((address_space(3))) unsigned int lds_u32;
#else
#define HAVE_GLL 0
#endif

__global__ __launch_bounds__(TPB, 3) void kan_mfma_kernel(
    const float* __restrict__ x, const _Float16* __restrict__ W0t,
    const _Float16* __restrict__ W1t, const float* __restrict__ bias0,
    const float* __restrict__ bias1, float* __restrict__ out)
{
    __shared__ char smem[LDS_TOT];
    const int tid  = threadIdx.x;
    const int lane = tid & 63;
    const int wid  = tid >> 6;          // 4 waves, disjoint 32-row strips
    const int gq   = lane >> 4;         // k-group 0..3
    const int lm   = lane & 15;
    const int wavebase = wid * 32;
    const long rowbase = (long)blockIdx.x * BM;

    // stage 8KB chunk: per wave 2 x (64 lanes x 16B = 1KB); LDS dest linear.
    auto stageChunk = [&](const char* gsrc_chunk, int bufoff) {
#if HAVE_GLL
        const char* gs = gsrc_chunk + wid * 2048 + lane * 16;
        char* ls = smem + W_OFF + bufoff + wid * 2048;
        __builtin_amdgcn_global_load_lds((glb_u32*)gs, (lds_u32*)ls, 16, 0, 0);
        __builtin_amdgcn_global_load_lds((glb_u32*)(gs + 1024), (lds_u32*)(ls + 1024), 16, 0, 0);
#else
        float4 a = *(const float4*)(gsrc_chunk + tid * 32);
        float4 b = *(const float4*)(gsrc_chunk + tid * 32 + 16);
        *(float4*)(smem + W_OFF + bufoff + tid * 32)      = a;
        *(float4*)(smem + W_OFF + bufoff + tid * 32 + 16) = b;
#endif
    };

#if __has_builtin(__builtin_amdgcn_cvt_pkrtz)
    auto pk2 = [](float a, float b) -> f16x2 {
        return (f16x2)__builtin_amdgcn_cvt_pkrtz(a, b);
    };
#else
    auto pk2 = [](float a, float b) -> f16x2 {
        return f16x2{(_Float16)a, (_Float16)b};
    };
#endif
#if __has_builtin(__builtin_amdgcn_rcpf)
    auto frcp = [](float a) -> float { return __builtin_amdgcn_rcpf(a); };
#else
    auto frcp = [](float a) -> float { return 1.0f / a; };
#endif

    // features for 8 values -> 4 fragments {base, gi, s1, s1*gi}
    auto buildFeats4 = [&](const float* v, f16x8* dst) {
        union U { f16x8 v8; f16x2 h2[4]; } u0, u1, u2, u3;
        #pragma unroll
        for (int q = 0; q < 4; ++q) {
            float va = v[2 * q], vb = v[2 * q + 1];
            float ba = va * frcp(1.0f + __expf(-va));
            float bb = vb * frcp(1.0f + __expf(-vb));
            float ga = fminf(fmaxf(va, -1.f), 1.f) + 1.f;   // [0,2]
            float gb = fminf(fmaxf(vb, -1.f), 1.f) + 1.f;
            float s1a = (ga >= 1.f) ? 1.f : 0.f;
            float s1b = (gb >= 1.f) ? 1.f : 0.f;
            float sga = (ga >= 1.f) ? ga : 0.f;
            float sgb = (gb >= 1.f) ? gb : 0.f;
            u0.h2[q] = pk2(ba, bb);
            u1.h2[q] = pk2(ga, gb);
            u2.h2[q] = pk2(s1a, s1b);
            u3.h2[q] = pk2(sga, sgb);
        }
        dst[0] = u0.v8; dst[1] = u1.v8; dst[2] = u2.v8; dst[3] = u3.v8;
    };

    // ---------------- bias fragments (per-column, fp32) ----------------
    float b0v[8], b1v[4];
    #pragma unroll
    for (int nf = 0; nf < 8; ++nf) b0v[nf] = bias0[nf * 16 + lm];
    #pragma unroll
    for (int nf = 0; nf < 4; ++nf) b1v[nf] = bias1[nf * 16 + lm];

    // ---------------- load x values for both i-halves ----------------
    float v0[2][8], v1[2][8];           // [mi][e]: ih=0 (i=gq*8..), ih=1 (i=32+gq*8..)
    #pragma unroll
    for (int mi = 0; mi < 2; ++mi) {
        const float* xp = x + (rowbase + wavebase + mi * 16 + lm) * 64 + gq * 8;
        float4 a0 = *(const float4*)(xp);
        float4 a1 = *(const float4*)(xp + 4);
        float4 a2 = *(const float4*)(xp + 32);
        float4 a3 = *(const float4*)(xp + 36);
        v0[mi][0]=a0.x; v0[mi][1]=a0.y; v0[mi][2]=a0.z; v0[mi][3]=a0.w;
        v0[mi][4]=a1.x; v0[mi][5]=a1.y; v0[mi][6]=a1.z; v0[mi][7]=a1.w;
        v1[mi][0]=a2.x; v1[mi][1]=a2.y; v1[mi][2]=a2.z; v1[mi][3]=a2.w;
        v1[mi][4]=a3.x; v1[mi][5]=a3.y; v1[mi][6]=a3.z; v1[mi][7]=a3.w;
    }

    // ---------------- layer 0: 8 steps, W staged 8KB/step (async DMA) ----------------
    f32x4 acc[2][8] = {};
    {
        const char* w0 = (const char*)W0t;
        const int lb0 = (gq * 128 + lm) * 16;    // + nf*256 within chunk

        stageChunk(w0, 0);                        // chunk 0 -> buf 0
        f16x8 fr[2][4];
        buildFeats4(v0[0], fr[0]);
        buildFeats4(v0[1], fr[1]);
        __syncthreads();                          // chunk 0 staged (vmcnt drain)

#define L0_STEP(S, C) do {                                                    \
        if ((S) < 7)                                                          \
            stageChunk(w0 + ((S) + 1) * 8192, (((S) + 1) & 1) * 8192);        \
        const char* wb = smem + W_OFF + ((S) & 1) * 8192;                     \
        f16x8 bt[8];                                                          \
        _Pragma("unroll")                                                     \
        for (int nf = 0; nf < 8; ++nf)                                        \
            bt[nf] = *(const f16x8*)(wb + lb0 + nf * 256);                    \
        _Pragma("unroll")                                                     \
        for (int mi = 0; mi < 2; ++mi) {                                      \
            f16x8 a = fr[mi][C];                                              \
            _Pragma("unroll")                                                 \
            for (int nf = 0; nf < 8; ++nf)                                    \
                acc[mi][nf] = __builtin_amdgcn_mfma_f32_16x16x32_f16(         \
                    a, bt[nf], acc[mi][nf], 0, 0, 0);                         \
        }                                                                     \
        __syncthreads();                                                      \
    } while (0)

        L0_STEP(0, 0); L0_STEP(1, 1); L0_STEP(2, 2); L0_STEP(3, 3);
        buildFeats4(v1[0], fr[0]);
        buildFeats4(v1[1], fr[1]);
        L0_STEP(4, 0); L0_STEP(5, 1); L0_STEP(6, 2); L0_STEP(7, 3);
#undef L0_STEP
    }

    // h + bias0 -> H LDS f16 ; then stage L1 stage0 (8KB) into buf 0
    {
        #pragma unroll
        for (int mi = 0; mi < 2; ++mi)
            #pragma unroll
            for (int nf = 0; nf < 8; ++nf)
                #pragma unroll
                for (int rg = 0; rg < 4; ++rg)
                    *(_Float16*)(smem + (wavebase + mi * 16 + gq * 4 + rg) * HSTRIDE
                                 + (nf * 16 + lm) * 2) = (_Float16)(acc[mi][nf][rg] + b0v[nf]);
        __syncthreads();                 // H visible; all L0 W-buffer reads done
        stageChunk((const char*)W1t, 0);
        __syncthreads();                 // L1 stage0 staged
    }

    // ---------------- layer 1: 8 stages x 2 steps, 8KB/stage (async DMA) ----------------
    f32x4 accO[2][4] = {};
    {
        const char* w1 = (const char*)W1t;
        const int lb1 = (gq * 64 + lm) * 16;     // + nf*256 within 4KB chunk
        f16x8 fr[2][4];

#define L1_SUB(BUFOFF, C) do {                                                \
        const char* wb = smem + W_OFF + (BUFOFF);                             \
        f16x8 bt[4];                                                          \
        _Pragma("unroll")                                                     \
        for (int nf = 0; nf < 4; ++nf)                                        \
            bt[nf] = *(const f16x8*)(wb + lb1 + nf * 256);                    \
        _Pragma("unroll")                                                     \
        for (int mi = 0; mi < 2; ++mi) {                                      \
            f16x8 a = fr[mi][C];                                              \
            _Pragma("unroll")                                                 \
            for (int nf = 0; nf < 4; ++nf)                                    \
                accO[mi][nf] = __builtin_amdgcn_mfma_f32_16x16x32_f16(        \
                    a, bt[nf], accO[mi][nf], 0, 0, 0);                        \
        }                                                                     \
    } while (0)

#define L1_STAGE(SG, C0, C1) do {                                            \
        if ((SG) < 7)                                                         \
            stageChunk(w1 + ((SG) + 1) * 8192, (((SG) + 1) & 1) * 8192);      \
        L1_SUB(((SG) & 1) * 8192, C0);                                        \
        L1_SUB(((SG) & 1) * 8192 + 4096, C1);                                 \
        __syncthreads();                                                      \
    } while (0)

#define L1_FEATS(HALF, IH) do {                                               \
        _Pragma("unroll")                                                     \
        for (int mi = 0; mi < 2; ++mi) {                                      \
            const char* hrow = smem + (wavebase + mi * 16 + lm) * HSTRIDE;    \
            f16x8 hv = *(const f16x8*)(hrow + ((HALF) * 64 + (IH) * 32 + gq * 8) * 2); \
            float v[8];                                                       \
            _Pragma("unroll")                                                 \
            for (int e = 0; e < 8; ++e) v[e] = (float)hv[e];                  \
            buildFeats4(v, fr[mi]);                                           \
        }                                                                     \
    } while (0)

        L1_FEATS(0, 0);
        L1_STAGE(0, 0, 1); L1_STAGE(1, 2, 3);
        L1_FEATS(0, 1);
        L1_STAGE(2, 0, 1); L1_STAGE(3, 2, 3);
        L1_FEATS(1, 0);
        L1_STAGE(4, 0, 1); L1_STAGE(5, 2, 3);
        L1_FEATS(1, 1);
        L1_STAGE(6, 0, 1); L1_STAGE(7, 2, 3);
#undef L1_SUB
#undef L1_STAGE
#undef L1_FEATS
    }

    // ---------------- store out (+bias1) ----------------
    float* og = out + (rowbase + wavebase) * 64;
    #pragma unroll
    for (int mi = 0; mi < 2; ++mi)
        #pragma unroll
        for (int nf = 0; nf < 4; ++nf)
            #pragma unroll
            for (int rg = 0; rg < 4; ++rg)
                og[(mi * 16 + gq * 4 + rg) * 64 + nf * 16 + lm] = accO[mi][nf][rg] + b1v[nf];
}

// ------------- pre-kernel: fold weights + wide-parallel bias -------------
// blocks 0..255: weight fold.  blocks 256..271: bias0 (16 blk x 8 cols, 2-iter).
// blocks 272..287: bias1 (16 blk x 4 cols, 2-iter).
// Feature order q: {base, gi, s1, s1*gi}.  Per edge:
//   P0 = cp.bv0 ; Q0 = cp.(bv1-bv0) ; P1 = cp.(2bv1-bv2) ; Q1 = cp.(bv2-bv1)
//   w = imp * {bw, sw*Q0, sw*(P1-P0), sw*(Q1-Q0)};  bias_j = sum_i imp*sw*P0
// W0t flat f = ((s*4+g)*128+n)*8+e ; s=ih*4+q ; i=ih*32+g*8+e ; edge=i*128+n
// W1t flat f = (((half*8+s)*4+g)*64+n)*8+e ; i2=half*64+ih*32+g*8+e
__global__ __launch_bounds__(256) void kan_combine_w(
    const float* __restrict__ cp0, const float* __restrict__ bw0,
    const float* __restrict__ sw0, const float* __restrict__ imp0,
    const float* __restrict__ cp1, const float* __restrict__ bw1,
    const float* __restrict__ sw1, const float* __restrict__ imp1,
    _Float16* __restrict__ W0t, _Float16* __restrict__ W1t,
    float* __restrict__ bias0, float* __restrict__ bias1)
{
    float bvv[3][5];
    #pragma unroll
    for (int g = 0; g < 3; ++g) {
        float gv = (float)g - 1.0f;
        float e[5]; float s = 0.f;
        #pragma unroll
        for (int i = 0; i < 5; ++i) {
            float cc = -0.8125f + 0.325f * (float)i;
            float d  = (gv - cc) * (1.0f / 0.65f);
            e[i] = __expf(-d * d); s += e[i];
        }
        float inv = 1.0f / (s + 1e-6f);
        #pragma unroll
        for (int i = 0; i < 5; ++i) bvv[g][i] = e[i] * inv;
    }

    auto wval = [&](const float* cp, float bw, float sw, float imp, int q) -> float {
        if (q == 0) return imp * bw;
        float P0 = 0.f, Q0 = 0.f, P1 = 0.f, Q1 = 0.f;
        #pragma unroll
        for (int c = 0; c < 5; ++c) {
            P0 += cp[c] * bvv[0][c];
            Q0 += cp[c] * (bvv[1][c] - bvv[0][c]);
            P1 += cp[c] * (2.f * bvv[1][c] - bvv[2][c]);
            Q1 += cp[c] * (bvv[2][c] - bvv[1][c]);
        }
        float r = (q == 1) ? Q0 : (q == 2) ? (P1 - P0) : (Q1 - Q0);
        return imp * sw * r;
    };
    auto p0val = [&](const float* cp) -> float {
        float P0 = 0.f;
        #pragma unroll
        for (int c = 0; c < 5; ++c) P0 += cp[c] * bvv[0][c];
        return P0;
    };

    const int bx = blockIdx.x;
    const int t  = threadIdx.x;

    if (bx < 256) {
        int f = bx * 256 + t;
        if (f < 32768) {
            int e = f & 7, n = (f >> 3) & 127, g = (f >> 10) & 3, s = f >> 12;
            int ih = s >> 2, q = s & 3;
            int i = ih * 32 + g * 8 + e;
            int edge = i * 128 + n;
            W0t[f] = (_Float16)wval(cp0 + edge * 5, bw0[edge], sw0[edge], imp0[edge], q);
        } else {
            int f2 = f - 32768;
            int e = f2 & 7, n = (f2 >> 3) & 63, g = (f2 >> 9) & 3;
            int tq = f2 >> 11;
            int half = tq >> 3, s = tq & 7;
            int ih = s >> 2, q = s & 3;
            int i2 = half * 64 + ih * 32 + g * 8 + e;
            int edge = i2 * 64 + n;
            W1t[f2] = (_Float16)wval(cp1 + edge * 5, bw1[edge], sw1[edge], imp1[edge], q);
        }
    } else if (bx < 272) {
        __shared__ float part[256];
        int bb = bx - 256;
        int jj = t >> 5, split = t & 31;
        int j = bb * 8 + jj;
        float s = 0.f;
        #pragma unroll
        for (int k = 0; k < 2; ++k) {
            int i = split * 2 + k;
            int edge = i * 128 + j;
            s += imp0[edge] * sw0[edge] * p0val(cp0 + edge * 5);
        }
        part[t] = s;
        __syncthreads();
        if (t < 8) {
            float acc = 0.f;
            #pragma unroll
            for (int k = 0; k < 32; ++k) acc += part[t * 32 + k];
            bias0[bb * 8 + t] = acc;
        }
    } else {
        __shared__ float part[256];
        int bb = bx - 272;
        int jj = t >> 6, split = t & 63;
        int j = bb * 4 + jj;
        float s = 0.f;
        #pragma unroll
        for (int k = 0; k < 2; ++k) {
            int i2 = split * 2 + k;
            int edge = i2 * 64 + j;
            s += imp1[edge] * sw1[edge] * p0val(cp1 + edge * 5);
        }
        part[t] = s;
        __syncthreads();
        if (t < 4) {
            float acc = 0.f;
            #pragma unroll
            for (int k = 0; k < 64; ++k) acc += part[t * 64 + k];
            bias1[bb * 4 + t] = acc;
        }
    }
}

// ===================== fallback: proven fp32 kernel (round 2) =====================
#define NTHR 256
#define JT 32
#define WS8 8

#define STAGE_L0(JBASE) do {                                                  \
    _Pragma("unroll")                                                         \
    for (int p = 0; p < 8; ++p) {                                             \
        int idx = tid + p * NTHR;                                             \
        int i  = idx >> 5;                                                    \
        int jj = idx & 31;                                                    \
        int e  = i * 128 + (JBASE) + jj;                                      \
        float im = imp0[e];                                                   \
        float wb = bw0[e] * im;                                               \
        float ws = sw0[e] * im;                                               \
        const float* cp = cp0 + e * 5;                                        \
        float* wp = wbuf + idx * WS8;                                         \
        wp[0] = wb;                                                           \
        wp[1] = ws * cp[0]; wp[2] = ws * cp[1]; wp[3] = ws * cp[2];           \
        wp[4] = ws * cp[3]; wp[5] = ws * cp[4];                               \
    }                                                                         \
} while (0)

#define STAGE_L1(IBASE, JBASE) do {                                           \
    _Pragma("unroll")                                                         \
    for (int p = 0; p < 8; ++p) {                                             \
        int idx = tid + p * NTHR;                                             \
        int ii = idx >> 5;                                                    \
        int jj = idx & 31;                                                    \
        int e  = ((IBASE) + ii) * 64 + (JBASE) + jj;                          \
        float im = imp1[e];                                                   \
        float wb = bw1[e] * im;                                               \
        float ws = sw1[e] * im;                                               \
        const float* cp = cp1 + e * 5;                                        \
        float* wp = wbuf + idx * WS8;                                         \
        wp[0] = wb;                                                           \
        wp[1] = ws * cp[0]; wp[2] = ws * cp[1]; wp[3] = ws * cp[2];           \
        wp[4] = ws * cp[3]; wp[5] = ws * cp[4];                               \
    }                                                                         \
} while (0)

#define COMPUTE_TILE(ACC) do {                                                \
    _Pragma("unroll 2")                                                       \
    for (int i = 0; i < 64; ++i) {                                            \
        float v  = vbuf[i][tid];                                              \
        float sg = 1.0f / (1.0f + __expf(-v));                                \
        float base = v * sg;                                                  \
        float xc = fminf(fmaxf(v, -1.0f), 1.0f);                              \
        float gi = xc + 1.0f;                                                 \
        int lo = (int)gi; lo = (lo > 2) ? 2 : lo;                             \
        float fr = gi - (float)lo;                                            \
        int hi = (fr > 0.0f) ? (lo + 1) : lo;                                 \
        float b0 = bvt[lo][0]; b0 += (bvt[hi][0] - b0) * fr;                  \
        float b1 = bvt[lo][1]; b1 += (bvt[hi][1] - b1) * fr;                  \
        float b2 = bvt[lo][2]; b2 += (bvt[hi][2] - b2) * fr;                  \
        float b3 = bvt[lo][3]; b3 += (bvt[hi][3] - b3) * fr;                  \
        float b4 = bvt[lo][4]; b4 += (bvt[hi][4] - b4) * fr;                  \
        const float* wr = wbuf + i * (JT * WS8);                              \
        _Pragma("unroll")                                                     \
        for (int jj = 0; jj < JT; ++jj) {                                     \
            const float* wp = wr + jj * WS8;                                  \
            float a = ACC[jj];                                                \
            a = fmaf(wp[0], base, a);                                         \
            a = fmaf(wp[1], b0, a);                                           \
            a = fmaf(wp[2], b1, a);                                           \
            a = fmaf(wp[3], b2, a);                                           \
            a = fmaf(wp[4], b3, a);                                           \
            a = fmaf(wp[5], b4, a);                                           \
            ACC[jj] = a;                                                      \
        }                                                                     \
    }                                                                         \
} while (0)

__global__ __launch_bounds__(NTHR) void kan_fused_kernel(
    const float* __restrict__ x,
    const float* __restrict__ cp0, const float* __restrict__ bw0,
    const float* __restrict__ sw0, const float* __restrict__ imp0,
    const float* __restrict__ cp1, const float* __restrict__ bw1,
    const float* __restrict__ sw1, const float* __restrict__ imp1,
    float* __restrict__ out)
{
    __shared__ float vbuf[64][NTHR + 1];
    __shared__ float wbuf[64 * JT * WS8];
    __shared__ float bvt[3][8];

    const int tid = threadIdx.x;

    if (tid < 3) {
        float gv = -1.0f + (float)tid;
        float e[5];
        float s = 0.0f;
        #pragma unroll
        for (int i = 0; i < 5; ++i) {
            float c = -0.8125f + 0.325f * (float)i;
            float d = (gv - c) * (1.0f / 0.65f);
            e[i] = expf(-d * d);
            s += e[i];
        }
        float inv = 1.0f / (s + 1e-6f);
        #pragma unroll
        for (int i = 0; i < 5; ++i) bvt[tid][i] = e[i] * inv;
    }

    {
        const float4* xg = (const float4*)(x + (size_t)blockIdx.x * (NTHR * 64));
        #pragma unroll
        for (int it = 0; it < 16; ++it) {
            int e4 = tid + it * NTHR;
            float4 v = xg[e4];
            int r  = e4 >> 4;
            int ib = (e4 & 15) << 2;
            vbuf[ib + 0][r] = v.x;
            vbuf[ib + 1][r] = v.y;
            vbuf[ib + 2][r] = v.z;
            vbuf[ib + 3][r] = v.w;
        }
    }
    __syncthreads();

    float h0[32] = {}, h1[32] = {}, h2[32] = {}, h3[32] = {};
    STAGE_L0(0);   __syncthreads(); COMPUTE_TILE(h0); __syncthreads();
    STAGE_L0(32);  __syncthreads(); COMPUTE_TILE(h1); __syncthreads();
    STAGE_L0(64);  __syncthreads(); COMPUTE_TILE(h2); __syncthreads();
    STAGE_L0(96);  __syncthreads(); COMPUTE_TILE(h3); __syncthreads();

    #pragma unroll
    for (int i = 0; i < 32; ++i) vbuf[i][tid] = h0[i];
    #pragma unroll
    for (int i = 0; i < 32; ++i) vbuf[32 + i][tid] = h1[i];

    float o0[32] = {}, o1[32] = {};
    STAGE_L1(0, 0);   __syncthreads(); COMPUTE_TILE(o0); __syncthreads();
    STAGE_L1(0, 32);  __syncthreads(); COMPUTE_TILE(o1); __syncthreads();

    #pragma unroll
    for (int i = 0; i < 32; ++i) vbuf[i][tid] = h2[i];
    #pragma unroll
    for (int i = 0; i < 32; ++i) vbuf[32 + i][tid] = h3[i];

    STAGE_L1(64, 0);  __syncthreads(); COMPUTE_TILE(o0); __syncthreads();
    STAGE_L1(64, 32); __syncthreads(); COMPUTE_TILE(o1);

    float4* og = (float4*)(out + (size_t)blockIdx.x * (NTHR * 64) + (size_t)tid * 64);
    #pragma unroll
    for (int q = 0; q < 8; ++q)
        og[q] = make_float4(o0[4 * q + 0], o0[4 * q + 1], o0[4 * q + 2], o0[4 * q + 3]);
    #pragma unroll
    for (int q = 0; q < 8; ++q)
        og[8 + q] = make_float4(o1[4 * q + 0], o1[4 * q + 1], o1[4 * q + 2], o1[4 * q + 3]);
}

// =================================== launch ===================================
extern "C" void kernel_launch(void* const* d_in, const int* in_sizes, int n_in,
                              void* d_out, int out_size, void* d_ws, size_t ws_size,
                              hipStream_t stream) {
    const float* x    = (const float*)d_in[0];
    const float* cp0  = (const float*)d_in[1];
    const float* bw0  = (const float*)d_in[2];
    const float* sw0  = (const float*)d_in[3];
    const float* imp0 = (const float*)d_in[4];
    const float* cp1  = (const float*)d_in[5];
    const float* bw1  = (const float*)d_in[6];
    const float* sw1  = (const float*)d_in[7];
    const float* imp1 = (const float*)d_in[8];
    float* out = (float*)d_out;

    const int B = in_sizes[0] / 64;                 // 131072
    const size_t need = 65536 * sizeof(_Float16) + 192 * sizeof(float);

    if (ws_size >= need && (B % BM) == 0) {
        _Float16* W0t = (_Float16*)d_ws;
        _Float16* W1t = W0t + 32768;
        float* bias0 = (float*)(W1t + 32768);
        float* bias1 = bias0 + 128;
        kan_combine_w<<<288, 256, 0, stream>>>(cp0, bw0, sw0, imp0,
                                               cp1, bw1, sw1, imp1,
                                               W0t, W1t, bias0, bias1);
        kan_mfma_kernel<<<B / BM, TPB, 0, stream>>>(x, W0t, W1t, bias0, bias1, out);
    } else {
        kan_fused_kernel<<<B / NTHR, NTHR, 0, stream>>>(
            x, cp0, bw0, sw0, imp0, cp1, bw1, sw1, imp1, out);
    }
}